// Round 7
// baseline (1333.126 us; speedup 1.0000x reference)
//
#include <hip/hip_runtime.h>
#include <hip/hip_bf16.h>
#include <math.h>

#define C 21
#define H 512
#define W 512
#define HW (H*W)
#define CHW (C*HW)
#define N_ITERS 5
#define RSP 6
#define KSP 13
#define RBI 8
#define KBI 17
#define LIST_CAP 4096

// workspace layout (float offsets)
#define KSP_OFF   0
#define KBI_OFF   16
#define NSP_OFF   64      // stores 1/nsp
#define NBI_OFF   576     // stores 1/nbi
#define M1_OFF    1088
#define M2_OFF    1536
#define NCOND_OFF 2048    // N_ITERS ints
#define S1_OFF    2064    // N_ITERS*C
#define S2_OFF    2176    // N_ITERS*C
#define LIST_OFF  2304    // N_ITERS*LIST_CAP ints -> ends 22784
#define CONTB_OFF 22784   // LIST_CAP*C floats -> ends 108800
#define UB_OFF    131072                  // CHW f32
#define QB_OFF    (UB_OFF + CHW)          // CHW f32
#define T1_OFF    (QB_OFF + CHW)          // CHW bf16 = CHW/2 floats
#define T2_OFF    (T1_OFF + CHW/2)        // CHW bf16

#define REP16(F) F(0) F(1) F(2) F(3) F(4) F(5) F(6) F(7) F(8) F(9) F(10) \
                 F(11) F(12) F(13) F(14) F(15)
#define REP21(F) F(0) F(1) F(2) F(3) F(4) F(5) F(6) F(7) F(8) F(9) F(10) \
                 F(11) F(12) F(13) F(14) F(15) F(16) F(17) F(18) F(19) F(20)
#define REP32(F) F(0) F(1) F(2) F(3) F(4) F(5) F(6) F(7) F(8) F(9) F(10) \
                 F(11) F(12) F(13) F(14) F(15) F(16) F(17) F(18) F(19) F(20) \
                 F(21) F(22) F(23) F(24) F(25) F(26) F(27) F(28) F(29) F(30) F(31)

__device__ __forceinline__ float bf2f(unsigned short u) {
  return __uint_as_float(((unsigned)u) << 16);
}
__device__ __forceinline__ unsigned packbf(float a, float b) {
  __hip_bfloat16 ha = __float2bfloat16(a), hb = __float2bfloat16(b);
  unsigned short ua = *(unsigned short*)&ha, ub = *(unsigned short*)&hb;
  return (unsigned)ua | ((unsigned)ub << 16);
}

__global__ __launch_bounds__(512) void k_setup(float* ws, const float* skw,
                                               const float* bkw, const float* cm) {
  int tid = threadIdx.x;
  if (tid == 0) {
    float s = 0.f;
    for (int i = 0; i < KSP; ++i) {
      float t = (float)(i - RSP);
      float v = expf(-0.5f * (t / 3.0f) * (t / 3.0f));
      ws[KSP_OFF + i] = v; s += v;
    }
    for (int i = 0; i < KSP; ++i) ws[KSP_OFF + i] /= s;
    s = 0.f;
    for (int i = 0; i < KBI; ++i) {
      float t = (float)(i - RBI);
      float v = expf(-0.5f * (t / 160.0f) * (t / 160.0f));
      ws[KBI_OFF + i] = v; s += v;
    }
    for (int i = 0; i < KBI; ++i) ws[KBI_OFF + i] /= s;
  }
  __syncthreads();
  if (tid < H) {
    float nsp = 0.f, nbi = 0.f;
    for (int t = 0; t < KSP; ++t) { int x = tid + t - RSP; if (x >= 0 && x < H) nsp += ws[KSP_OFF + t]; }
    for (int t = 0; t < KBI; ++t) { int x = tid + t - RBI; if (x >= 0 && x < H) nbi += ws[KBI_OFF + t]; }
    ws[NSP_OFF + tid] = 1.f / nsp;
    ws[NBI_OFF + tid] = 1.f / nbi;
  }
  if (tid < C * C) {
    int i = tid / C, j = tid % C;
    float m1 = 0.f, m2 = 0.f;
    for (int k = 0; k < C; ++k) {
      m1 += cm[i * C + k] * skw[k * C + j];
      m2 += cm[i * C + k] * bkw[k * C + j];
    }
    ws[M1_OFF + tid] = m1;
    ws[M2_OFF + tid] = m2;
  }
  if (tid < N_ITERS * C) { ws[S1_OFF + tid] = 0.f; ws[S2_OFF + tid] = 0.f; }
  if (tid < N_ITERS) ((int*)(ws + NCOND_OFF))[tid] = 0;
}

// compact per-sp_id pixel lists (runs once per call)
__global__ __launch_bounds__(256) void k_spt(const int* __restrict__ sp_map,
                                             int* __restrict__ ncond,
                                             int* __restrict__ list) {
  int p = blockIdx.x * 256 + threadIdx.x;
  int h = p >> 9, w = p & 511;
  int v = sp_map[w * H + h];
#pragma unroll
  for (int i = 0; i < N_ITERS; ++i)
    if (v == 250 + 7 * i) {
      int slot = atomicAdd(&ncond[i], 1);
      if (slot < LIST_CAP) list[i * LIST_CAP + slot] = p;
    }
}

// (H,W,C) -> (C,H,W)
__global__ __launch_bounds__(256) void k_tin(const float* __restrict__ in,
                                             float* __restrict__ outb) {
  __shared__ float t[C * 257];
  int tid = threadIdx.x;
  size_t p0 = (size_t)blockIdx.x * 256;
  size_t fbase = p0 * C;
#pragma unroll
  for (int i = 0; i < C; ++i) {
    int e = i * 256 + tid;
    int p = e / C, c = e % C;
    t[c * 257 + p] = in[fbase + e];
  }
  __syncthreads();
#pragma unroll
  for (int c = 0; c < C; ++c)
    outb[(size_t)c * HW + p0 + tid] = t[c * 257 + tid];
}

// (C,H,W) -> (H,W,C)
__global__ __launch_bounds__(256) void k_tout(const float* __restrict__ qb,
                                              float* __restrict__ out) {
  __shared__ float t[C * 257];
  int tid = threadIdx.x;
  size_t p0 = (size_t)blockIdx.x * 256;
#pragma unroll
  for (int c = 0; c < C; ++c)
    t[c * 257 + tid] = qb[(size_t)c * HW + p0 + tid];
  __syncthreads();
  size_t fbase = p0 * C;
#pragma unroll
  for (int i = 0; i < C; ++i) {
    int e = i * 256 + tid;
    int p = e / C, c = e % C;
    out[fbase + e] = t[c * 257 + p];
  }
}

// clique pass A: per-channel reduction sums over cond pixels -> global S1/S2
__global__ __launch_bounds__(256) void k_cliqueA(const float* __restrict__ qin,
                                                 float* __restrict__ ws, int iter) {
  int tid = threadIdx.x;
  const int* ncond = (const int*)(ws + NCOND_OFF);
  const int* list = (const int*)(ws + LIST_OFF) + iter * LIST_CAP;
  int n = ncond[iter]; if (n > LIST_CAP) n = LIST_CAP;
#define D1(i) float s1_##i = 0.f, s2_##i = 0.f;
  REP21(D1)
#undef D1
  for (int j = blockIdx.x * 256 + tid; j < n; j += 1024) {
    int p = list[j];
    float m = -1e30f;
#define LQ(i) float q##i = qin[(i) * HW + p]; m = fmaxf(m, q##i);
    REP21(LQ)
#undef LQ
    float s = 0.f;
#define EX(i) q##i = __expf(q##i - m); s += q##i;
    REP21(EX)
#undef EX
    float inv = 1.f / s;
    float smax = 0.f;
#define NM(i) q##i *= inv; smax = fmaxf(smax, q##i);
    REP21(NM)
#undef NM
#define AC(i) { s1_##i += __expf(q##i); \
                float A = (q##i == smax) ? smax : q##i + smax; \
                s2_##i += __expf(A); }
    REP21(AC)
#undef AC
  }
#define RED(x) x += __shfl_xor(x, 32); x += __shfl_xor(x, 16); x += __shfl_xor(x, 8); \
               x += __shfl_xor(x, 4); x += __shfl_xor(x, 2); x += __shfl_xor(x, 1);
#define RD(i) RED(s1_##i) RED(s2_##i)
  REP21(RD)
#undef RD
#undef RED
  if ((tid & 63) == 0) {
#define AT(i) atomicAdd(&ws[S1_OFF + iter * C + (i)], s1_##i); \
              atomicAdd(&ws[S2_OFF + iter * C + (i)], s2_##i);
    REP21(AT)
#undef AT
  }
}

// clique pass B: per-cond-pixel cont values into contb
__global__ __launch_bounds__(256) void k_cliqueB(const float* __restrict__ qin,
                                                 float* __restrict__ ws,
                                                 const float* __restrict__ loww,
                                                 const float* __restrict__ highw,
                                                 int iter) {
  int tid = threadIdx.x;
  const int* ncond = (const int*)(ws + NCOND_OFF);
  const int* list = (const int*)(ws + LIST_OFF) + iter * LIST_CAP;
  int n = ncond[iter]; if (n > LIST_CAP) n = LIST_CAP;
  float HWn = (float)(HW - n);
#define LB(i) float lb1_##i = logf(HWn + ws[S1_OFF + iter * C + (i)]); \
              float lb2_##i = logf(HWn + ws[S2_OFF + iter * C + (i)]);
  REP21(LB)
#undef LB
  float high0 = highw[0], high1 = highw[1];
  float* contb = ws + CONTB_OFF;
  for (int j = blockIdx.x * 256 + tid; j < n; j += 1024) {
    int p = list[j];
    float m = -1e30f;
#define LQ2(i) float q##i = qin[(i) * HW + p]; m = fmaxf(m, q##i);
    REP21(LQ2)
#undef LQ2
    float s = 0.f;
#define EX2(i) q##i = __expf(q##i - m); s += q##i;
    REP21(EX2)
#undef EX2
    float inv = 1.f / s;
    float smax = 0.f;
#define NM2(i) q##i *= inv; smax = fmaxf(smax, q##i);
    REP21(NM2)
#undef NM2
#define CW(i) { float A = (q##i == smax) ? smax : q##i + smax; \
                float ft = lb1_##i / q##i; \
                float ft2 = lb2_##i / A; \
                contb[j * C + (i)] = loww[i] * ft + high0 * (1.f - ft) \
                                   + loww[C + (i)] * ft2 + high1 * (1.f - ft2); }
    REP21(CW)
#undef CW
  }
}

// softmax + channel-mix, 2 adjacent pixels/thread, float2 loads, bf16x2 stores
__global__ __launch_bounds__(256) void k_smmix(const float* __restrict__ qin,
                                               unsigned* __restrict__ t1o,
                                               unsigned* __restrict__ t2o,
                                               const float* __restrict__ ws) {
  __shared__ float lm1[C * 24], lm2[C * 24];
  int tid = threadIdx.x;
  for (int e = tid; e < C * C; e += 256) {
    int r = e / C, cc = e - r * C;
    lm1[r * 24 + cc] = ws[M1_OFF + e];
    lm2[r * 24 + cc] = ws[M2_OFF + e];
  }
  __syncthreads();
  int b2 = blockIdx.x * 256 + tid;   // float2 index within channel
  const float2* q2 = (const float2*)qin;
  float ma = -1e30f, mb = -1e30f;
#define LQ(i) float2 v##i = q2[(size_t)(i) * (HW/2) + b2]; \
              ma = fmaxf(ma, v##i.x); mb = fmaxf(mb, v##i.y);
  REP21(LQ)
#undef LQ
  float sa = 0.f, sb = 0.f;
#define EQ(i) v##i.x = __expf(v##i.x - ma); sa += v##i.x; \
              v##i.y = __expf(v##i.y - mb); sb += v##i.y;
  REP21(EQ)
#undef EQ
  float ia = 1.f / sa, ib = 1.f / sb;
#define NQ(i) v##i.x *= ia; v##i.y *= ib;
  REP21(NQ)
#undef NQ
  for (int i = 0; i < C; ++i) {
    const float* r1 = lm1 + i * 24;
    const float* r2 = lm2 + i * 24;
    float t1a = 0.f, t1b = 0.f, t2a = 0.f, t2b = 0.f;
#define MIX(c) { float m1v = r1[c], m2v = r2[c]; \
                 t1a += m1v * v##c.x; t1b += m1v * v##c.y; \
                 t2a += m2v * v##c.x; t2b += m2v * v##c.y; }
    REP21(MIX)
#undef MIX
    t1o[(size_t)i * (HW/2) + b2] = packbf(t1a, t1b);
    t2o[(size_t)i * (HW/2) + b2] = packbf(t2a, t2b);
  }
}

// fused 2D blur + norm + q-update. 128x32 tile, bf16 inputs, XCD-chunk swizzle.
__global__ __launch_bounds__(256) void k_blur2d(
    const unsigned short* __restrict__ t1, const unsigned short* __restrict__ t2,
    const float* __restrict__ u, float* __restrict__ outq,
    const float* __restrict__ ws, const float* __restrict__ highw) {
  __shared__ float asmem[32 * 152], bsmem[32 * 152];
  __shared__ float ktsp[KSP], ktbi[KBI];
  int tid = threadIdx.x;
  if (tid < KSP) ktsp[tid] = ws[KSP_OFF + tid];
  if (tid < KBI) ktbi[tid] = ws[KBI_OFF + tid];
  __syncthreads();
  // bijective XCD-chunk swizzle: 1344 blocks = 8 * 168
  int l = blockIdx.x;
  int nl = (l & 7) * 168 + (l >> 3);
  int c = nl >> 6;                 // / 64
  int rem = nl & 63;
  int h0 = (rem >> 2) * 32;
  int w0 = (rem & 3) * 128;
  size_t cbase = (size_t)c * HW;
  if (tid < 144) {
    int col = w0 - 8 + tid;
    bool okc = (col >= 0 && col < W);
    const unsigned short* s1 = t1 + cbase;
    const unsigned short* s2 = t2 + cbase;
#define DECLA(o) float a##o = 0.f;
    REP32(DECLA)
#undef DECLA
#pragma unroll
    for (int j = 0; j < 44; ++j) {
      int hh = h0 - 6 + j;
      float v = (okc && hh >= 0 && hh < H) ? bf2f(s1[hh * W + col]) : 0.f;
#define ACCA(o) { int t = j - (o); if (t >= 0 && t < KSP) a##o += ktsp[t] * v; }
      REP32(ACCA)
#undef ACCA
    }
#define STORA(o) asmem[(o) * 152 + tid] = a##o;
    REP32(STORA)
#undef STORA
#define DECLB(o) float b##o = 0.f;
    REP32(DECLB)
#undef DECLB
#pragma unroll
    for (int j = 0; j < 48; ++j) {
      int hh = h0 - 8 + j;
      float v = (okc && hh >= 0 && hh < H) ? bf2f(s2[hh * W + col]) : 0.f;
#define ACCB(o) { int t = j - (o); if (t >= 0 && t < KBI) b##o += ktbi[t] * v; }
      REP32(ACCB)
#undef ACCB
    }
#define STORB(o) bsmem[(o) * 152 + tid] = b##o;
    REP32(STORB)
#undef STORB
  }
  __syncthreads();
  float cc = highw[0] + highw[1];
#define HOUT(k) { \
    int o = tid + (k) * 256; \
    int r = o >> 7, wc = o & 127; \
    float a = 0.f, b = 0.f; \
    _Pragma("unroll") \
    for (int t = 0; t < KSP; ++t) a += ktsp[t] * asmem[r * 152 + wc + 2 + t]; \
    _Pragma("unroll") \
    for (int t = 0; t < KBI; ++t) b += ktbi[t] * bsmem[r * 152 + wc + t]; \
    int h = h0 + r, w = w0 + wc; \
    float inv_nsp = ws[NSP_OFF + h] * ws[NSP_OFF + w]; \
    float inv_nbi = ws[NBI_OFF + h] * ws[NBI_OFF + w]; \
    size_t idx = cbase + (size_t)h * W + w; \
    outq[idx] = u[idx] - (a * inv_nsp + b * inv_nbi) - cc; }
  REP16(HOUT)
#undef HOUT
}

// patch cond pixels: out += cc - cont
__global__ __launch_bounds__(256) void k_contfix(float* __restrict__ outq,
                                                 const float* __restrict__ ws,
                                                 const float* __restrict__ highw,
                                                 int iter) {
  const int* ncond = (const int*)(ws + NCOND_OFF);
  int n = ncond[iter]; if (n > LIST_CAP) n = LIST_CAP;
  int e = blockIdx.x * 256 + threadIdx.x;
  if (e >= n * C) return;
  int j = e / C, c = e - j * C;
  const int* list = (const int*)(ws + LIST_OFF) + iter * LIST_CAP;
  int p = list[j];
  float cc = highw[0] + highw[1];
  outq[(size_t)c * HW + p] += cc - ws[CONTB_OFF + e];
}

extern "C" void kernel_launch(void* const* d_in, const int* in_sizes, int n_in,
                              void* d_out, int out_size, void* d_ws, size_t ws_size,
                              hipStream_t stream) {
  const float* unaries = (const float*)d_in[0];
  const int* sp_map = (const int*)d_in[2];
  const float* skw = (const float*)d_in[3];
  const float* bkw = (const float*)d_in[4];
  const float* loww = (const float*)d_in[5];
  const float* highw = (const float*)d_in[6];
  const float* cm = (const float*)d_in[7];
  float* out = (float*)d_out;
  float* ws = (float*)d_ws;
  float* ubuf = ws + UB_OFF;
  float* qbuf = ws + QB_OFF;
  unsigned* t1u = (unsigned*)(ws + T1_OFF);
  unsigned* t2u = (unsigned*)(ws + T2_OFF);
  const unsigned short* t1s = (const unsigned short*)(ws + T1_OFF);
  const unsigned short* t2s = (const unsigned short*)(ws + T2_OFF);
  int* ncond = (int*)(ws + NCOND_OFF);
  int* list = (int*)(ws + LIST_OFF);

  k_setup<<<1, 512, 0, stream>>>(ws, skw, bkw, cm);
  k_spt<<<HW / 256, 256, 0, stream>>>(sp_map, ncond, list);
  k_tin<<<HW / 256, 256, 0, stream>>>(unaries, ubuf);
  for (int i = 0; i < N_ITERS; ++i) {
    const float* qin = (i == 0) ? ubuf : qbuf;
    k_cliqueA<<<4, 256, 0, stream>>>(qin, ws, i);
    k_cliqueB<<<4, 256, 0, stream>>>(qin, ws, loww, highw, i);
    k_smmix<<<HW / 512, 256, 0, stream>>>(qin, t1u, t2u, ws);
    k_blur2d<<<1344, 256, 0, stream>>>(t1s, t2s, ubuf, qbuf, ws, highw);
    k_contfix<<<128, 256, 0, stream>>>(qbuf, ws, highw, i);
  }
  k_tout<<<HW / 256, 256, 0, stream>>>(qbuf, out);
}

// Round 8
// 636.155 us; speedup vs baseline: 2.0956x; 2.0956x over previous
//
#include <hip/hip_runtime.h>
#include <hip/hip_bf16.h>
#include <math.h>

#define C 21
#define H 512
#define W 512
#define HW (H*W)
#define CHW (C*HW)
#define N_ITERS 5
#define RSP 6
#define KSP 13
#define RBI 8
#define KBI 17
#define LIST_CAP 4096

// workspace layout (float offsets)
#define KSP_OFF   0
#define KBI_OFF   16
#define NSP_OFF   64      // stores 1/nsp
#define NBI_OFF   576     // stores 1/nbi
#define M1_OFF    1088
#define M2_OFF    1536
#define NCOND_OFF 2048    // N_ITERS ints
#define S1_OFF    2064    // N_ITERS*C
#define S2_OFF    2176    // N_ITERS*C
#define LIST_OFF  2304    // N_ITERS*LIST_CAP ints -> ends 22784
#define CONTB_OFF 22784   // LIST_CAP*C floats -> ends 108800
#define UB_OFF    131072                  // CHW f32
#define QB_OFF    (UB_OFF + CHW)          // CHW f32
#define T1_OFF    (QB_OFF + CHW)          // CHW bf16 = CHW/2 floats
#define T2_OFF    (T1_OFF + CHW/2)        // CHW bf16
#define UBH_OFF   (T2_OFF + CHW/2)        // CHW bf16

#define REP8(F) F(0) F(1) F(2) F(3) F(4) F(5) F(6) F(7)
#define REP16(F) F(0) F(1) F(2) F(3) F(4) F(5) F(6) F(7) F(8) F(9) F(10) \
                 F(11) F(12) F(13) F(14) F(15)
#define REP21(F) F(0) F(1) F(2) F(3) F(4) F(5) F(6) F(7) F(8) F(9) F(10) \
                 F(11) F(12) F(13) F(14) F(15) F(16) F(17) F(18) F(19) F(20)

__device__ __forceinline__ float bf2f(unsigned short u) {
  return __uint_as_float(((unsigned)u) << 16);
}
__device__ __forceinline__ unsigned short f2bfu(float a) {
  __hip_bfloat16 h = __float2bfloat16(a);
  return *(unsigned short*)&h;
}
__device__ __forceinline__ unsigned packbf(float a, float b) {
  return (unsigned)f2bfu(a) | ((unsigned)f2bfu(b) << 16);
}

__global__ __launch_bounds__(512) void k_setup(float* ws, const float* skw,
                                               const float* bkw, const float* cm) {
  int tid = threadIdx.x;
  if (tid == 0) {
    float s = 0.f;
    for (int i = 0; i < KSP; ++i) {
      float t = (float)(i - RSP);
      float v = expf(-0.5f * (t / 3.0f) * (t / 3.0f));
      ws[KSP_OFF + i] = v; s += v;
    }
    for (int i = 0; i < KSP; ++i) ws[KSP_OFF + i] /= s;
    s = 0.f;
    for (int i = 0; i < KBI; ++i) {
      float t = (float)(i - RBI);
      float v = expf(-0.5f * (t / 160.0f) * (t / 160.0f));
      ws[KBI_OFF + i] = v; s += v;
    }
    for (int i = 0; i < KBI; ++i) ws[KBI_OFF + i] /= s;
  }
  __syncthreads();
  if (tid < H) {
    float nsp = 0.f, nbi = 0.f;
    for (int t = 0; t < KSP; ++t) { int x = tid + t - RSP; if (x >= 0 && x < H) nsp += ws[KSP_OFF + t]; }
    for (int t = 0; t < KBI; ++t) { int x = tid + t - RBI; if (x >= 0 && x < H) nbi += ws[KBI_OFF + t]; }
    ws[NSP_OFF + tid] = 1.f / nsp;
    ws[NBI_OFF + tid] = 1.f / nbi;
  }
  if (tid < C * C) {
    int i = tid / C, j = tid % C;
    float m1 = 0.f, m2 = 0.f;
    for (int k = 0; k < C; ++k) {
      m1 += cm[i * C + k] * skw[k * C + j];
      m2 += cm[i * C + k] * bkw[k * C + j];
    }
    ws[M1_OFF + tid] = m1;
    ws[M2_OFF + tid] = m2;
  }
  if (tid < N_ITERS * C) { ws[S1_OFF + tid] = 0.f; ws[S2_OFF + tid] = 0.f; }
  if (tid < N_ITERS) ((int*)(ws + NCOND_OFF))[tid] = 0;
}

// compact per-sp_id pixel lists (runs once per call)
__global__ __launch_bounds__(256) void k_spt(const int* __restrict__ sp_map,
                                             int* __restrict__ ncond,
                                             int* __restrict__ list) {
  int p = blockIdx.x * 256 + threadIdx.x;
  int h = p >> 9, w = p & 511;
  int v = sp_map[w * H + h];
#pragma unroll
  for (int i = 0; i < N_ITERS; ++i)
    if (v == 250 + 7 * i) {
      int slot = atomicAdd(&ncond[i], 1);
      if (slot < LIST_CAP) list[i * LIST_CAP + slot] = p;
    }
}

// (H,W,C) -> (C,H,W) fp32, plus bf16 shadow copy of u
__global__ __launch_bounds__(256) void k_tin(const float* __restrict__ in,
                                             float* __restrict__ outb,
                                             unsigned short* __restrict__ ubh) {
  __shared__ float t[C * 257];
  int tid = threadIdx.x;
  size_t p0 = (size_t)blockIdx.x * 256;
  size_t fbase = p0 * C;
#pragma unroll
  for (int i = 0; i < C; ++i) {
    int e = i * 256 + tid;
    int p = e / C, c = e % C;
    t[c * 257 + p] = in[fbase + e];
  }
  __syncthreads();
#pragma unroll
  for (int c = 0; c < C; ++c) {
    float v = t[c * 257 + tid];
    outb[(size_t)c * HW + p0 + tid] = v;
    ubh[(size_t)c * HW + p0 + tid] = f2bfu(v);
  }
}

// (C,H,W) -> (H,W,C)
__global__ __launch_bounds__(256) void k_tout(const float* __restrict__ qb,
                                              float* __restrict__ out) {
  __shared__ float t[C * 257];
  int tid = threadIdx.x;
  size_t p0 = (size_t)blockIdx.x * 256;
#pragma unroll
  for (int c = 0; c < C; ++c)
    t[c * 257 + tid] = qb[(size_t)c * HW + p0 + tid];
  __syncthreads();
  size_t fbase = p0 * C;
#pragma unroll
  for (int i = 0; i < C; ++i) {
    int e = i * 256 + tid;
    int p = e / C, c = e % C;
    out[fbase + e] = t[c * 257 + p];
  }
}

// clique pass A: per-channel reduction sums over cond pixels -> global S1/S2
__global__ __launch_bounds__(256) void k_cliqueA(const float* __restrict__ qin,
                                                 float* __restrict__ ws, int iter) {
  int tid = threadIdx.x;
  const int* ncond = (const int*)(ws + NCOND_OFF);
  const int* list = (const int*)(ws + LIST_OFF) + iter * LIST_CAP;
  int n = ncond[iter]; if (n > LIST_CAP) n = LIST_CAP;
#define D1(i) float s1_##i = 0.f, s2_##i = 0.f;
  REP21(D1)
#undef D1
  for (int j = blockIdx.x * 256 + tid; j < n; j += 1024) {
    int p = list[j];
    float m = -1e30f;
#define LQ(i) float q##i = qin[(i) * HW + p]; m = fmaxf(m, q##i);
    REP21(LQ)
#undef LQ
    float s = 0.f;
#define EX(i) q##i = __expf(q##i - m); s += q##i;
    REP21(EX)
#undef EX
    float inv = 1.f / s;
    float smax = 0.f;
#define NM(i) q##i *= inv; smax = fmaxf(smax, q##i);
    REP21(NM)
#undef NM
#define AC(i) { s1_##i += __expf(q##i); \
                float A = (q##i == smax) ? smax : q##i + smax; \
                s2_##i += __expf(A); }
    REP21(AC)
#undef AC
  }
#define RED(x) x += __shfl_xor(x, 32); x += __shfl_xor(x, 16); x += __shfl_xor(x, 8); \
               x += __shfl_xor(x, 4); x += __shfl_xor(x, 2); x += __shfl_xor(x, 1);
#define RD(i) RED(s1_##i) RED(s2_##i)
  REP21(RD)
#undef RD
#undef RED
  if ((tid & 63) == 0) {
#define AT(i) atomicAdd(&ws[S1_OFF + iter * C + (i)], s1_##i); \
              atomicAdd(&ws[S2_OFF + iter * C + (i)], s2_##i);
    REP21(AT)
#undef AT
  }
}

// clique pass B: per-cond-pixel cont values into contb
__global__ __launch_bounds__(256) void k_cliqueB(const float* __restrict__ qin,
                                                 float* __restrict__ ws,
                                                 const float* __restrict__ loww,
                                                 const float* __restrict__ highw,
                                                 int iter) {
  int tid = threadIdx.x;
  const int* ncond = (const int*)(ws + NCOND_OFF);
  const int* list = (const int*)(ws + LIST_OFF) + iter * LIST_CAP;
  int n = ncond[iter]; if (n > LIST_CAP) n = LIST_CAP;
  float HWn = (float)(HW - n);
#define LB(i) float lb1_##i = logf(HWn + ws[S1_OFF + iter * C + (i)]); \
              float lb2_##i = logf(HWn + ws[S2_OFF + iter * C + (i)]);
  REP21(LB)
#undef LB
  float high0 = highw[0], high1 = highw[1];
  float* contb = ws + CONTB_OFF;
  for (int j = blockIdx.x * 256 + tid; j < n; j += 1024) {
    int p = list[j];
    float m = -1e30f;
#define LQ2(i) float q##i = qin[(i) * HW + p]; m = fmaxf(m, q##i);
    REP21(LQ2)
#undef LQ2
    float s = 0.f;
#define EX2(i) q##i = __expf(q##i - m); s += q##i;
    REP21(EX2)
#undef EX2
    float inv = 1.f / s;
    float smax = 0.f;
#define NM2(i) q##i *= inv; smax = fmaxf(smax, q##i);
    REP21(NM2)
#undef NM2
#define CW(i) { float A = (q##i == smax) ? smax : q##i + smax; \
                float ft = lb1_##i / q##i; \
                float ft2 = lb2_##i / A; \
                contb[j * C + (i)] = loww[i] * ft + high0 * (1.f - ft) \
                                   + loww[C + (i)] * ft2 + high1 * (1.f - ft2); }
    REP21(CW)
#undef CW
  }
}

// softmax + channel-mix, 2 adjacent pixels/thread, float2 loads, bf16x2 stores
__global__ __launch_bounds__(256) void k_smmix(const float* __restrict__ qin,
                                               unsigned* __restrict__ t1o,
                                               unsigned* __restrict__ t2o,
                                               const float* __restrict__ ws) {
  __shared__ float lm1[C * 24], lm2[C * 24];
  int tid = threadIdx.x;
  for (int e = tid; e < C * C; e += 256) {
    int r = e / C, cc = e - r * C;
    lm1[r * 24 + cc] = ws[M1_OFF + e];
    lm2[r * 24 + cc] = ws[M2_OFF + e];
  }
  __syncthreads();
  int b2 = blockIdx.x * 256 + tid;   // float2 index within channel
  const float2* q2 = (const float2*)qin;
  float ma = -1e30f, mb = -1e30f;
#define LQ(i) float2 v##i = q2[(size_t)(i) * (HW/2) + b2]; \
              ma = fmaxf(ma, v##i.x); mb = fmaxf(mb, v##i.y);
  REP21(LQ)
#undef LQ
  float sa = 0.f, sb = 0.f;
#define EQ(i) v##i.x = __expf(v##i.x - ma); sa += v##i.x; \
              v##i.y = __expf(v##i.y - mb); sb += v##i.y;
  REP21(EQ)
#undef EQ
  float ia = 1.f / sa, ib = 1.f / sb;
#define NQ(i) v##i.x *= ia; v##i.y *= ib;
  REP21(NQ)
#undef NQ
  for (int i = 0; i < C; ++i) {
    const float* r1 = lm1 + i * 24;
    const float* r2 = lm2 + i * 24;
    float t1a = 0.f, t1b = 0.f, t2a = 0.f, t2b = 0.f;
#define MIX(c) { float m1v = r1[c], m2v = r2[c]; \
                 t1a += m1v * v##c.x; t1b += m1v * v##c.y; \
                 t2a += m2v * v##c.x; t2b += m2v * v##c.y; }
    REP21(MIX)
#undef MIX
    t1o[(size_t)i * (HW/2) + b2] = packbf(t1a, t1b);
    t2o[(size_t)i * (HW/2) + b2] = packbf(t2a, t2b);
  }
}

// fused 2D blur + norm + q-update. 128x16 tile (round-5 proven shape), bf16 in.
// Phase 1: threads 0..143 vertical-blur 144 halo columns into LDS.
// Phase 2: 256 threads horizontal taps from LDS, norm, u - pw - cc, write q.
__global__ __launch_bounds__(256) void k_blur2d(
    const unsigned short* __restrict__ t1, const unsigned short* __restrict__ t2,
    const unsigned short* __restrict__ uh, float* __restrict__ outq,
    const float* __restrict__ ws, const float* __restrict__ highw) {
  __shared__ float asmem[16 * 152], bsmem[16 * 152];
  __shared__ float ktsp[KSP], ktbi[KBI];
  int tid = threadIdx.x;
  if (tid < KSP) ktsp[tid] = ws[KSP_OFF + tid];
  if (tid < KBI) ktbi[tid] = ws[KBI_OFF + tid];
  __syncthreads();
  // bijective XCD-chunk swizzle: 2688 blocks = 8 * 336
  int l = blockIdx.x;
  int nl = (l & 7) * 336 + (l >> 3);
  int c = nl >> 7;                 // 128 tiles per channel
  int rem = nl & 127;
  int h0 = (rem >> 2) * 16;
  int w0 = (rem & 3) * 128;
  size_t cbase = (size_t)c * HW;
  if (tid < 144) {
    int col = w0 - 8 + tid;
    bool okc = (col >= 0 && col < W);
    const unsigned short* s1 = t1 + cbase;
    const unsigned short* s2 = t2 + cbase;
#define DECL(o) float a##o = 0.f, b##o = 0.f;
    REP16(DECL)
#undef DECL
#pragma unroll
    for (int j = 0; j < 28; ++j) {
      int hh = h0 - 6 + j;
      float v = (okc && hh >= 0 && hh < H) ? bf2f(s1[hh * W + col]) : 0.f;
#define ACCA(o) { int t = j - (o); if (t >= 0 && t < KSP) a##o += ktsp[t] * v; }
      REP16(ACCA)
#undef ACCA
    }
#pragma unroll
    for (int j = 0; j < 32; ++j) {
      int hh = h0 - 8 + j;
      float v = (okc && hh >= 0 && hh < H) ? bf2f(s2[hh * W + col]) : 0.f;
#define ACCB(o) { int t = j - (o); if (t >= 0 && t < KBI) b##o += ktbi[t] * v; }
      REP16(ACCB)
#undef ACCB
    }
#define STOR(o) asmem[(o) * 152 + tid] = a##o; bsmem[(o) * 152 + tid] = b##o;
    REP16(STOR)
#undef STOR
  }
  __syncthreads();
  float cc = highw[0] + highw[1];
#define HOUT(k) { \
    int o = tid + (k) * 256; \
    int r = o >> 7, wc = o & 127; \
    float a = 0.f, b = 0.f; \
    _Pragma("unroll") \
    for (int t = 0; t < KSP; ++t) a += ktsp[t] * asmem[r * 152 + wc + 2 + t]; \
    _Pragma("unroll") \
    for (int t = 0; t < KBI; ++t) b += ktbi[t] * bsmem[r * 152 + wc + t]; \
    int h = h0 + r, w = w0 + wc; \
    float inv_nsp = ws[NSP_OFF + h] * ws[NSP_OFF + w]; \
    float inv_nbi = ws[NBI_OFF + h] * ws[NBI_OFF + w]; \
    size_t idx = cbase + (size_t)h * W + w; \
    outq[idx] = bf2f(uh[idx]) - (a * inv_nsp + b * inv_nbi) - cc; }
  REP8(HOUT)
#undef HOUT
}

// patch cond pixels: out += cc - cont
__global__ __launch_bounds__(256) void k_contfix(float* __restrict__ outq,
                                                 const float* __restrict__ ws,
                                                 const float* __restrict__ highw,
                                                 int iter) {
  const int* ncond = (const int*)(ws + NCOND_OFF);
  int n = ncond[iter]; if (n > LIST_CAP) n = LIST_CAP;
  int e = blockIdx.x * 256 + threadIdx.x;
  if (e >= n * C) return;
  int j = e / C, c = e - j * C;
  const int* list = (const int*)(ws + LIST_OFF) + iter * LIST_CAP;
  int p = list[j];
  float cc = highw[0] + highw[1];
  outq[(size_t)c * HW + p] += cc - ws[CONTB_OFF + e];
}

extern "C" void kernel_launch(void* const* d_in, const int* in_sizes, int n_in,
                              void* d_out, int out_size, void* d_ws, size_t ws_size,
                              hipStream_t stream) {
  const float* unaries = (const float*)d_in[0];
  const int* sp_map = (const int*)d_in[2];
  const float* skw = (const float*)d_in[3];
  const float* bkw = (const float*)d_in[4];
  const float* loww = (const float*)d_in[5];
  const float* highw = (const float*)d_in[6];
  const float* cm = (const float*)d_in[7];
  float* out = (float*)d_out;
  float* ws = (float*)d_ws;
  float* ubuf = ws + UB_OFF;
  float* qbuf = ws + QB_OFF;
  unsigned* t1u = (unsigned*)(ws + T1_OFF);
  unsigned* t2u = (unsigned*)(ws + T2_OFF);
  const unsigned short* t1s = (const unsigned short*)(ws + T1_OFF);
  const unsigned short* t2s = (const unsigned short*)(ws + T2_OFF);
  unsigned short* ubh = (unsigned short*)(ws + UBH_OFF);
  int* ncond = (int*)(ws + NCOND_OFF);
  int* list = (int*)(ws + LIST_OFF);

  k_setup<<<1, 512, 0, stream>>>(ws, skw, bkw, cm);
  k_spt<<<HW / 256, 256, 0, stream>>>(sp_map, ncond, list);
  k_tin<<<HW / 256, 256, 0, stream>>>(unaries, ubuf, ubh);
  for (int i = 0; i < N_ITERS; ++i) {
    const float* qin = (i == 0) ? ubuf : qbuf;
    k_cliqueA<<<4, 256, 0, stream>>>(qin, ws, i);
    k_cliqueB<<<4, 256, 0, stream>>>(qin, ws, loww, highw, i);
    k_smmix<<<HW / 512, 256, 0, stream>>>(qin, t1u, t2u, ws);
    k_blur2d<<<2688, 256, 0, stream>>>(t1s, t2s, ubh, qbuf, ws, highw);
    k_contfix<<<128, 256, 0, stream>>>(qbuf, ws, highw, i);
  }
  k_tout<<<HW / 256, 256, 0, stream>>>(qbuf, out);
}

// Round 9
// 407.412 us; speedup vs baseline: 3.2722x; 1.5615x over previous
//
#include <hip/hip_runtime.h>
#include <hip/hip_bf16.h>
#include <math.h>
#include <utility>

#define C 21
#define H 512
#define W 512
#define HW (H*W)
#define CHW (C*HW)
#define N_ITERS 5
#define RSP 6
#define KSP 13
#define RBI 8
#define KBI 17
#define LIST_CAP 4096

// workspace layout (float offsets)
#define KSP_OFF   0
#define KBI_OFF   16
#define NSP_OFF   64      // stores 1/nsp
#define NBI_OFF   576     // stores 1/nbi
#define M1_OFF    1088
#define M2_OFF    1536
#define NCOND_OFF 2048    // N_ITERS ints
#define S1_OFF    2064    // N_ITERS*C
#define S2_OFF    2176    // N_ITERS*C
#define LIST_OFF  2304    // N_ITERS*LIST_CAP ints -> ends 22784
#define CONTB_OFF 22784   // LIST_CAP*C floats -> ends 108800
#define UB_OFF    131072                  // CHW f32
#define QB_OFF    (UB_OFF + CHW)          // CHW f32
#define T12_OFF   (QB_OFF + CHW)          // CHW dwords (bf16 t1 | t2<<16)
#define UBH_OFF   (T12_OFF + CHW)         // CHW bf16

#define REP21(F) F(0) F(1) F(2) F(3) F(4) F(5) F(6) F(7) F(8) F(9) F(10) \
                 F(11) F(12) F(13) F(14) F(15) F(16) F(17) F(18) F(19) F(20)

template <int... Js, typename F>
__device__ __forceinline__ void sfor(std::integer_sequence<int, Js...>, F&& f) {
  (f(std::integral_constant<int, Js>{}), ...);
}
#define SFOR(N, body) sfor(std::make_integer_sequence<int, N>{}, body)

__device__ __forceinline__ float bf2f(unsigned short u) {
  return __uint_as_float(((unsigned)u) << 16);
}
__device__ __forceinline__ unsigned short f2bfu(float a) {
  __hip_bfloat16 h = __float2bfloat16(a);
  return *(unsigned short*)&h;
}
__device__ __forceinline__ unsigned packbf(float a, float b) {
  return (unsigned)f2bfu(a) | ((unsigned)f2bfu(b) << 16);
}

__global__ __launch_bounds__(512) void k_setup(float* ws, const float* skw,
                                               const float* bkw, const float* cm) {
  int tid = threadIdx.x;
  if (tid == 0) {
    float s = 0.f;
    for (int i = 0; i < KSP; ++i) {
      float t = (float)(i - RSP);
      float v = expf(-0.5f * (t / 3.0f) * (t / 3.0f));
      ws[KSP_OFF + i] = v; s += v;
    }
    for (int i = 0; i < KSP; ++i) ws[KSP_OFF + i] /= s;
    s = 0.f;
    for (int i = 0; i < KBI; ++i) {
      float t = (float)(i - RBI);
      float v = expf(-0.5f * (t / 160.0f) * (t / 160.0f));
      ws[KBI_OFF + i] = v; s += v;
    }
    for (int i = 0; i < KBI; ++i) ws[KBI_OFF + i] /= s;
  }
  __syncthreads();
  if (tid < H) {
    float nsp = 0.f, nbi = 0.f;
    for (int t = 0; t < KSP; ++t) { int x = tid + t - RSP; if (x >= 0 && x < H) nsp += ws[KSP_OFF + t]; }
    for (int t = 0; t < KBI; ++t) { int x = tid + t - RBI; if (x >= 0 && x < H) nbi += ws[KBI_OFF + t]; }
    ws[NSP_OFF + tid] = 1.f / nsp;
    ws[NBI_OFF + tid] = 1.f / nbi;
  }
  if (tid < C * C) {
    int i = tid / C, j = tid % C;
    float m1 = 0.f, m2 = 0.f;
    for (int k = 0; k < C; ++k) {
      m1 += cm[i * C + k] * skw[k * C + j];
      m2 += cm[i * C + k] * bkw[k * C + j];
    }
    ws[M1_OFF + tid] = m1;
    ws[M2_OFF + tid] = m2;
  }
  if (tid < N_ITERS * C) { ws[S1_OFF + tid] = 0.f; ws[S2_OFF + tid] = 0.f; }
  if (tid < N_ITERS) ((int*)(ws + NCOND_OFF))[tid] = 0;
}

// compact per-sp_id pixel lists (runs once per call)
__global__ __launch_bounds__(256) void k_spt(const int* __restrict__ sp_map,
                                             int* __restrict__ ncond,
                                             int* __restrict__ list) {
  int p = blockIdx.x * 256 + threadIdx.x;
  int h = p >> 9, w = p & 511;
  int v = sp_map[w * H + h];
#pragma unroll
  for (int i = 0; i < N_ITERS; ++i)
    if (v == 250 + 7 * i) {
      int slot = atomicAdd(&ncond[i], 1);
      if (slot < LIST_CAP) list[i * LIST_CAP + slot] = p;
    }
}

// (H,W,C) -> (C,H,W) fp32, plus bf16 shadow copy of u
__global__ __launch_bounds__(256) void k_tin(const float* __restrict__ in,
                                             float* __restrict__ outb,
                                             unsigned short* __restrict__ ubh) {
  __shared__ float t[C * 257];
  int tid = threadIdx.x;
  size_t p0 = (size_t)blockIdx.x * 256;
  size_t fbase = p0 * C;
#pragma unroll
  for (int i = 0; i < C; ++i) {
    int e = i * 256 + tid;
    int p = e / C, c = e % C;
    t[c * 257 + p] = in[fbase + e];
  }
  __syncthreads();
#pragma unroll
  for (int c = 0; c < C; ++c) {
    float v = t[c * 257 + tid];
    outb[(size_t)c * HW + p0 + tid] = v;
    ubh[(size_t)c * HW + p0 + tid] = f2bfu(v);
  }
}

// (C,H,W) -> (H,W,C)
__global__ __launch_bounds__(256) void k_tout(const float* __restrict__ qb,
                                              float* __restrict__ out) {
  __shared__ float t[C * 257];
  int tid = threadIdx.x;
  size_t p0 = (size_t)blockIdx.x * 256;
#pragma unroll
  for (int c = 0; c < C; ++c)
    t[c * 257 + tid] = qb[(size_t)c * HW + p0 + tid];
  __syncthreads();
  size_t fbase = p0 * C;
#pragma unroll
  for (int i = 0; i < C; ++i) {
    int e = i * 256 + tid;
    int p = e / C, c = e % C;
    out[fbase + e] = t[c * 257 + p];
  }
}

// clique pass A: per-channel reduction sums over cond pixels -> global S1/S2
__global__ __launch_bounds__(256) void k_cliqueA(const float* __restrict__ qin,
                                                 float* __restrict__ ws, int iter) {
  int tid = threadIdx.x;
  const int* ncond = (const int*)(ws + NCOND_OFF);
  const int* list = (const int*)(ws + LIST_OFF) + iter * LIST_CAP;
  int n = ncond[iter]; if (n > LIST_CAP) n = LIST_CAP;
#define D1(i) float s1_##i = 0.f, s2_##i = 0.f;
  REP21(D1)
#undef D1
  for (int j = blockIdx.x * 256 + tid; j < n; j += 1024) {
    int p = list[j];
    float m = -1e30f;
#define LQ(i) float q##i = qin[(i) * HW + p]; m = fmaxf(m, q##i);
    REP21(LQ)
#undef LQ
    float s = 0.f;
#define EX(i) q##i = __expf(q##i - m); s += q##i;
    REP21(EX)
#undef EX
    float inv = 1.f / s;
    float smax = 0.f;
#define NM(i) q##i *= inv; smax = fmaxf(smax, q##i);
    REP21(NM)
#undef NM
#define AC(i) { s1_##i += __expf(q##i); \
                float A = (q##i == smax) ? smax : q##i + smax; \
                s2_##i += __expf(A); }
    REP21(AC)
#undef AC
  }
#define RED(x) x += __shfl_xor(x, 32); x += __shfl_xor(x, 16); x += __shfl_xor(x, 8); \
               x += __shfl_xor(x, 4); x += __shfl_xor(x, 2); x += __shfl_xor(x, 1);
#define RD(i) RED(s1_##i) RED(s2_##i)
  REP21(RD)
#undef RD
#undef RED
  if ((tid & 63) == 0) {
#define AT(i) atomicAdd(&ws[S1_OFF + iter * C + (i)], s1_##i); \
              atomicAdd(&ws[S2_OFF + iter * C + (i)], s2_##i);
    REP21(AT)
#undef AT
  }
}

// clique pass B: per-cond-pixel cont values into contb
__global__ __launch_bounds__(256) void k_cliqueB(const float* __restrict__ qin,
                                                 float* __restrict__ ws,
                                                 const float* __restrict__ loww,
                                                 const float* __restrict__ highw,
                                                 int iter) {
  int tid = threadIdx.x;
  const int* ncond = (const int*)(ws + NCOND_OFF);
  const int* list = (const int*)(ws + LIST_OFF) + iter * LIST_CAP;
  int n = ncond[iter]; if (n > LIST_CAP) n = LIST_CAP;
  float HWn = (float)(HW - n);
#define LB(i) float lb1_##i = logf(HWn + ws[S1_OFF + iter * C + (i)]); \
              float lb2_##i = logf(HWn + ws[S2_OFF + iter * C + (i)]);
  REP21(LB)
#undef LB
  float high0 = highw[0], high1 = highw[1];
  float* contb = ws + CONTB_OFF;
  for (int j = blockIdx.x * 256 + tid; j < n; j += 1024) {
    int p = list[j];
    float m = -1e30f;
#define LQ2(i) float q##i = qin[(i) * HW + p]; m = fmaxf(m, q##i);
    REP21(LQ2)
#undef LQ2
    float s = 0.f;
#define EX2(i) q##i = __expf(q##i - m); s += q##i;
    REP21(EX2)
#undef EX2
    float inv = 1.f / s;
    float smax = 0.f;
#define NM2(i) q##i *= inv; smax = fmaxf(smax, q##i);
    REP21(NM2)
#undef NM2
#define CW(i) { float A = (q##i == smax) ? smax : q##i + smax; \
                float ft = lb1_##i / q##i; \
                float ft2 = lb2_##i / A; \
                contb[j * C + (i)] = loww[i] * ft + high0 * (1.f - ft) \
                                   + loww[C + (i)] * ft2 + high1 * (1.f - ft2); }
    REP21(CW)
#undef CW
  }
}

// softmax + channel-mix, 2 adjacent pixels/thread, float2 loads,
// interleaved (t1|t2<<16) dword-per-pixel output via uint2 store
__global__ __launch_bounds__(256) void k_smmix(const float* __restrict__ qin,
                                               unsigned* __restrict__ t12,
                                               const float* __restrict__ ws) {
  __shared__ float lm1[C * 24], lm2[C * 24];
  int tid = threadIdx.x;
  for (int e = tid; e < C * C; e += 256) {
    int r = e / C, cc = e - r * C;
    lm1[r * 24 + cc] = ws[M1_OFF + e];
    lm2[r * 24 + cc] = ws[M2_OFF + e];
  }
  __syncthreads();
  int b2 = blockIdx.x * 256 + tid;   // float2 index within channel
  const float2* q2 = (const float2*)qin;
  float ma = -1e30f, mb = -1e30f;
#define LQ(i) float2 v##i = q2[(size_t)(i) * (HW/2) + b2]; \
              ma = fmaxf(ma, v##i.x); mb = fmaxf(mb, v##i.y);
  REP21(LQ)
#undef LQ
  float sa = 0.f, sb = 0.f;
#define EQ(i) v##i.x = __expf(v##i.x - ma); sa += v##i.x; \
              v##i.y = __expf(v##i.y - mb); sb += v##i.y;
  REP21(EQ)
#undef EQ
  float ia = 1.f / sa, ib = 1.f / sb;
#define NQ(i) v##i.x *= ia; v##i.y *= ib;
  REP21(NQ)
#undef NQ
  for (int i = 0; i < C; ++i) {
    const float* r1 = lm1 + i * 24;
    const float* r2 = lm2 + i * 24;
    float t1a = 0.f, t1b = 0.f, t2a = 0.f, t2b = 0.f;
#define MIX(c) { float m1v = r1[c], m2v = r2[c]; \
                 t1a += m1v * v##c.x; t1b += m1v * v##c.y; \
                 t2a += m2v * v##c.x; t2b += m2v * v##c.y; }
    REP21(MIX)
#undef MIX
    uint2 st;
    st.x = packbf(t1a, t2a);
    st.y = packbf(t1b, t2b);
    *reinterpret_cast<uint2*>(t12 + (size_t)i * HW + 2 * b2) = st;
  }
}

// fused 2D blur + norm + q-update. 128x16 tile, interleaved bf16 pair loads.
// Phase 1: threads 0..143 vertical-blur 144 halo columns (dword loads, 32-deep
// MLP via up-front static-indexed register loads) into LDS.
// Phase 2: 256 threads x 4 pairs: horizontal taps from LDS, norm from LDS
// tables, dword u load, float2 q store.
__global__ __launch_bounds__(256) void k_blur2d(
    const unsigned* __restrict__ t12, const unsigned* __restrict__ uh32,
    float* __restrict__ outq, const float* __restrict__ ws,
    const float* __restrict__ highw) {
  __shared__ float asmem[16 * 152], bsmem[16 * 152];
  __shared__ float ktsp[KSP], ktbi[KBI];
  __shared__ float nspw[128], nbiw[128], nsph[16], nbih[16];
  int tid = threadIdx.x;
  // bijective XCD-chunk swizzle: 2688 blocks = 8 * 336
  int l = blockIdx.x;
  int nl = (l & 7) * 336 + (l >> 3);
  int c = nl >> 7;                 // 128 tiles per channel
  int rem = nl & 127;
  int h0 = (rem >> 2) * 16;
  int w0 = (rem & 3) * 128;
  if (tid < KSP) ktsp[tid] = ws[KSP_OFF + tid];
  if (tid >= 32 && tid < 32 + KBI) ktbi[tid - 32] = ws[KBI_OFF + tid - 32];
  if (tid >= 64 && tid < 192) {
    int i = tid - 64;
    nspw[i] = ws[NSP_OFF + w0 + i];
    nbiw[i] = ws[NBI_OFF + w0 + i];
  }
  if (tid >= 192 && tid < 208) {
    int i = tid - 192;
    nsph[i] = ws[NSP_OFF + h0 + i];
    nbih[i] = ws[NBI_OFF + h0 + i];
  }
  __syncthreads();
  size_t cbase = (size_t)c * HW;
  if (tid < 144) {
    int col = w0 - 8 + tid;
    bool okc = (col >= 0 && col < W);
    const unsigned* s12 = t12 + cbase;
    unsigned lv[32];
    SFOR(32, [&](auto jc) {
      constexpr int j = decltype(jc)::value;
      int hh = h0 - 8 + j;
      lv[j] = (okc && hh >= 0 && hh < H) ? s12[(size_t)hh * W + col] : 0u;
    });
    float a[16], b[16];
    SFOR(16, [&](auto oc) {
      constexpr int o = decltype(oc)::value;
      a[o] = 0.f; b[o] = 0.f;
    });
    SFOR(32, [&](auto jc) {
      constexpr int j = decltype(jc)::value;
      float f1 = __uint_as_float(lv[j] << 16);
      float f2 = __uint_as_float(lv[j] & 0xFFFF0000u);
      SFOR(16, [&](auto oc) {
        constexpr int o = decltype(oc)::value;
        if constexpr (j - 2 - o >= 0 && j - 2 - o < KSP) a[o] += ktsp[j - 2 - o] * f1;
        if constexpr (j - o >= 0 && j - o < KBI) b[o] += ktbi[j - o] * f2;
      });
    });
    SFOR(16, [&](auto oc) {
      constexpr int o = decltype(oc)::value;
      asmem[o * 152 + tid] = a[o];
      bsmem[o * 152 + tid] = b[o];
    });
  }
  __syncthreads();
  float cc = highw[0] + highw[1];
#pragma unroll
  for (int k = 0; k < 4; ++k) {
    int o = tid + k * 256;         // pair index, 1024 pairs
    int r = o >> 6, wp = o & 63;
    int wl = 2 * wp;
    float a0 = 0.f, a1 = 0.f, b0 = 0.f, b1 = 0.f;
#pragma unroll
    for (int t = 0; t < KSP; ++t) {
      float kv = ktsp[t];
      a0 += kv * asmem[r * 152 + wl + 2 + t];
      a1 += kv * asmem[r * 152 + wl + 3 + t];
    }
#pragma unroll
    for (int t = 0; t < KBI; ++t) {
      float kv = ktbi[t];
      b0 += kv * bsmem[r * 152 + wl + t];
      b1 += kv * bsmem[r * 152 + wl + 1 + t];
    }
    size_t idx = cbase + (size_t)(h0 + r) * W + (w0 + wl);
    unsigned uv = uh32[idx >> 1];
    float u0 = __uint_as_float(uv << 16);
    float u1 = __uint_as_float(uv & 0xFFFF0000u);
    float pw0 = a0 * (nsph[r] * nspw[wl]) + b0 * (nbih[r] * nbiw[wl]);
    float pw1 = a1 * (nsph[r] * nspw[wl + 1]) + b1 * (nbih[r] * nbiw[wl + 1]);
    float2 res = make_float2(u0 - pw0 - cc, u1 - pw1 - cc);
    *reinterpret_cast<float2*>(outq + idx) = res;
  }
}

// patch cond pixels: out += cc - cont
__global__ __launch_bounds__(256) void k_contfix(float* __restrict__ outq,
                                                 const float* __restrict__ ws,
                                                 const float* __restrict__ highw,
                                                 int iter) {
  const int* ncond = (const int*)(ws + NCOND_OFF);
  int n = ncond[iter]; if (n > LIST_CAP) n = LIST_CAP;
  int e = blockIdx.x * 256 + threadIdx.x;
  if (e >= n * C) return;
  int j = e / C, c = e - j * C;
  const int* list = (const int*)(ws + LIST_OFF) + iter * LIST_CAP;
  int p = list[j];
  float cc = highw[0] + highw[1];
  outq[(size_t)c * HW + p] += cc - ws[CONTB_OFF + e];
}

extern "C" void kernel_launch(void* const* d_in, const int* in_sizes, int n_in,
                              void* d_out, int out_size, void* d_ws, size_t ws_size,
                              hipStream_t stream) {
  const float* unaries = (const float*)d_in[0];
  const int* sp_map = (const int*)d_in[2];
  const float* skw = (const float*)d_in[3];
  const float* bkw = (const float*)d_in[4];
  const float* loww = (const float*)d_in[5];
  const float* highw = (const float*)d_in[6];
  const float* cm = (const float*)d_in[7];
  float* out = (float*)d_out;
  float* ws = (float*)d_ws;
  float* ubuf = ws + UB_OFF;
  float* qbuf = ws + QB_OFF;
  unsigned* t12 = (unsigned*)(ws + T12_OFF);
  unsigned short* ubh = (unsigned short*)(ws + UBH_OFF);
  const unsigned* uh32 = (const unsigned*)(ws + UBH_OFF);
  int* ncond = (int*)(ws + NCOND_OFF);
  int* list = (int*)(ws + LIST_OFF);

  k_setup<<<1, 512, 0, stream>>>(ws, skw, bkw, cm);
  k_spt<<<HW / 256, 256, 0, stream>>>(sp_map, ncond, list);
  k_tin<<<HW / 256, 256, 0, stream>>>(unaries, ubuf, ubh);
  for (int i = 0; i < N_ITERS; ++i) {
    const float* qin = (i == 0) ? ubuf : qbuf;
    k_cliqueA<<<4, 256, 0, stream>>>(qin, ws, i);
    k_cliqueB<<<4, 256, 0, stream>>>(qin, ws, loww, highw, i);
    k_smmix<<<HW / 512, 256, 0, stream>>>(qin, t12, ws);
    k_blur2d<<<2688, 256, 0, stream>>>(t12, uh32, qbuf, ws, highw);
    k_contfix<<<128, 256, 0, stream>>>(qbuf, ws, highw, i);
  }
  k_tout<<<HW / 256, 256, 0, stream>>>(qbuf, out);
}